// Round 1
// baseline (734.332 us; speedup 1.0000x reference)
//
#include <hip/hip_runtime.h>

#define BB 2
#define HH 48
#define WW 48
#define CC 192
#define NHEADS 6
#define HD 32
#define KK 9
#define FF 486
#define NPIX (BB*HH*WW)   // 4608
#define SCALE 0.17677669529663687f  // 1/sqrt(32)

// v[n][c] = sum_k x[n][k] * v_w[c][k]
__global__ void gemm_v_kernel(const float* __restrict__ x, const float* __restrict__ vw,
                              float* __restrict__ v) {
    int idx = blockIdx.x * blockDim.x + threadIdx.x;
    if (idx >= NPIX * CC) return;
    int n = idx / CC, c = idx % CC;
    const float* xr = x + n * CC;
    const float* wr = vw + c * CC;
    float s = 0.f;
    #pragma unroll 4
    for (int k = 0; k < CC; ++k) s += xr[k] * wr[k];
    v[idx] = s;
}

// a[n][f] = sum_k x[n][k] * attn_w[f][k] + attn_b[f]
__global__ void gemm_a_kernel(const float* __restrict__ x, const float* __restrict__ aw,
                              const float* __restrict__ ab, float* __restrict__ a) {
    int idx = blockIdx.x * blockDim.x + threadIdx.x;
    if (idx >= NPIX * FF) return;
    int n = idx / FF, f = idx % FF;
    const float* xr = x + n * CC;
    const float* wr = aw + f * CC;
    float s = 0.f;
    #pragma unroll 4
    for (int k = 0; k < CC; ++k) s += xr[k] * wr[k];
    a[idx] = s + ab[f];
}

// one block (192 threads) per pixel: softmax + AV
__global__ void attn_kernel(const float* __restrict__ v, const float* __restrict__ a,
                            float* __restrict__ o) {
    int n = blockIdx.x;
    int tid = threadIdx.x; // 0..191
    int b = n / (HH * WW), rem = n % (HH * WW), h = rem / WW, w = rem % WW;
    __shared__ float p[FF];        // attention logits -> softmax probs
    __shared__ float vl[KK][CC];   // gathered v patches

    for (int f = tid; f < FF; f += CC) p[f] = a[n * FF + f];
    #pragma unroll
    for (int j = 0; j < KK; ++j) {
        int hh = h + j / 3 - 1, ww = w + j % 3 - 1;
        if (hh >= 0 && hh < HH && ww >= 0 && ww < WW)
            vl[j][tid] = v[((b * HH + hh) * WW + ww) * CC + tid];
        else
            vl[j][tid] = 0.f;
    }
    __syncthreads();

    // softmax: 54 rows (head,i), row offset in p is 9*tid since head*81+i*9 == 9*(head*9+i)
    if (tid < NHEADS * KK) {
        float* row = p + tid * KK;
        float t[KK];
        float m = -1e30f;
        #pragma unroll
        for (int j = 0; j < KK; ++j) { t[j] = row[j] * SCALE; m = fmaxf(m, t[j]); }
        float s = 0.f;
        #pragma unroll
        for (int j = 0; j < KK; ++j) { t[j] = __expf(t[j] - m); s += t[j]; }
        float inv = 1.f / s;
        #pragma unroll
        for (int j = 0; j < KK; ++j) row[j] = t[j] * inv;
    }
    __syncthreads();

    int head = tid / HD;
    const float* ph = p + head * 81;
    #pragma unroll
    for (int i = 0; i < KK; ++i) {
        float acc = 0.f;
        #pragma unroll
        for (int j = 0; j < KK; ++j) acc += ph[i * 9 + j] * vl[j][tid];
        o[(n * KK + i) * CC + tid] = acc;
    }
}

// folded[b,y,x,c] = sum over valid (ki,kj) of o[b, y+1-ki, x+1-kj, ki*3+kj, c]
__global__ void fold_kernel(const float* __restrict__ o, float* __restrict__ folded) {
    int idx = blockIdx.x * blockDim.x + threadIdx.x;
    if (idx >= NPIX * CC) return;
    int c = idx % CC, n = idx / CC;
    int b = n / (HH * WW), rem = n % (HH * WW), y = rem / WW, x = rem % WW;
    float s = 0.f;
    #pragma unroll
    for (int ki = 0; ki < 3; ++ki) {
        #pragma unroll
        for (int kj = 0; kj < 3; ++kj) {
            int hh = y + 1 - ki, ww = x + 1 - kj;
            if (hh >= 0 && hh < HH && ww >= 0 && ww < WW)
                s += o[(((b * HH + hh) * WW + ww) * KK + (ki * 3 + kj)) * CC + c];
        }
    }
    folded[idx] = s;
}

// out[n][c] = sum_k folded[n][k] * proj_w[c][k] + proj_b[c]
__global__ void proj_kernel(const float* __restrict__ folded, const float* __restrict__ pw,
                            const float* __restrict__ pb, float* __restrict__ out) {
    int idx = blockIdx.x * blockDim.x + threadIdx.x;
    if (idx >= NPIX * CC) return;
    int n = idx / CC, c = idx % CC;
    const float* xr = folded + n * CC;
    const float* wr = pw + c * CC;
    float s = 0.f;
    #pragma unroll 4
    for (int k = 0; k < CC; ++k) s += xr[k] * wr[k];
    out[idx] = s + pb[c];
}

extern "C" void kernel_launch(void* const* d_in, const int* in_sizes, int n_in,
                              void* d_out, int out_size, void* d_ws, size_t ws_size,
                              hipStream_t stream) {
    const float* x   = (const float*)d_in[0];
    const float* vw  = (const float*)d_in[1];
    const float* aw  = (const float*)d_in[2];
    const float* ab  = (const float*)d_in[3];
    const float* pw  = (const float*)d_in[4];
    const float* pb  = (const float*)d_in[5];
    float* out = (float*)d_out;

    float* v      = (float*)d_ws;                 // NPIX*CC
    float* a      = v + (size_t)NPIX * CC;        // NPIX*FF
    float* o      = a + (size_t)NPIX * FF;        // NPIX*KK*CC
    float* folded = o + (size_t)NPIX * KK * CC;   // NPIX*CC

    gemm_v_kernel<<<(NPIX * CC) / 256, 256, 0, stream>>>(x, vw, v);
    gemm_a_kernel<<<(NPIX * FF) / 256, 256, 0, stream>>>(x, aw, ab, a);
    attn_kernel<<<NPIX, CC, 0, stream>>>(v, a, o);
    fold_kernel<<<(NPIX * CC) / 256, 256, 0, stream>>>(o, folded);
    proj_kernel<<<(NPIX * CC) / 256, 256, 0, stream>>>(folded, pw, pb, out);
}

// Round 2
// 148.900 us; speedup vs baseline: 4.9317x; 4.9317x over previous
//
#include <hip/hip_runtime.h>

#define BB 2
#define HH 48
#define WW 48
#define CC 192
#define NHEADS 6
#define HD 32
#define KK 9
#define FF 486
#define NPIX (BB*HH*WW)   // 4608
#define SCALE 0.17677669529663687f  // 1/sqrt(32)

// ---------------------------------------------------------------------------
// Tiled GEMM: C[M][N] = X[M][K] * W[N][K]^T (+bias), K=192 fixed.
// 64x64 block tile, BK=16, 256 threads, 4x4 micro-tile per thread.
// ---------------------------------------------------------------------------
template<int N_DIM, bool HAS_BIAS>
__global__ __launch_bounds__(256) void gemm_xwt_kernel(
    const float* __restrict__ X, const float* __restrict__ W,
    const float* __restrict__ bias, float* __restrict__ C) {
    constexpr int Kd = CC;           // 192
    __shared__ float Xs[16][68];     // [k][m], stride 68 floats = 16B-aligned rows
    __shared__ float Ws[16][68];     // [k][n]

    const int tid = threadIdx.x;
    const int m0 = blockIdx.x * 64;
    const int n0 = blockIdx.y * 64;
    const int ty = tid / 16;         // 0..15 -> row group
    const int tx = tid % 16;         // 0..15 -> col group

    const int lr = tid / 4;          // 0..63: tile row to load
    const int lc = (tid % 4) * 4;    // 0,4,8,12: k-offset to load (float4)

    float acc[4][4] = {};

    for (int k0 = 0; k0 < Kd; k0 += 16) {
        // X tile: rows always in-bounds (M=4608 % 64 == 0)
        const float4 xv = *(const float4*)(X + (size_t)(m0 + lr) * Kd + k0 + lc);
        Xs[lc + 0][lr] = xv.x; Xs[lc + 1][lr] = xv.y;
        Xs[lc + 2][lr] = xv.z; Xs[lc + 3][lr] = xv.w;

        float4 wv = make_float4(0.f, 0.f, 0.f, 0.f);
        if (n0 + lr < N_DIM)
            wv = *(const float4*)(W + (size_t)(n0 + lr) * Kd + k0 + lc);
        Ws[lc + 0][lr] = wv.x; Ws[lc + 1][lr] = wv.y;
        Ws[lc + 2][lr] = wv.z; Ws[lc + 3][lr] = wv.w;

        __syncthreads();

        #pragma unroll
        for (int k = 0; k < 16; ++k) {
            float xr[4], wr[4];
            #pragma unroll
            for (int i = 0; i < 4; ++i) xr[i] = Xs[k][ty * 4 + i];
            #pragma unroll
            for (int j = 0; j < 4; ++j) wr[j] = Ws[k][tx * 4 + j];
            #pragma unroll
            for (int i = 0; i < 4; ++i)
                #pragma unroll
                for (int j = 0; j < 4; ++j)
                    acc[i][j] += xr[i] * wr[j];
        }
        __syncthreads();
    }

    #pragma unroll
    for (int i = 0; i < 4; ++i) {
        const int row = m0 + ty * 4 + i;
        #pragma unroll
        for (int j = 0; j < 4; ++j) {
            const int col = n0 + tx * 4 + j;
            if (col < N_DIM) {
                float r = acc[i][j];
                if (HAS_BIAS) r += bias[col];
                C[(size_t)row * N_DIM + col] = r;
            }
        }
    }
}

// ---------------------------------------------------------------------------
// Per-pixel attention: one 192-thread block per pixel.
// ---------------------------------------------------------------------------
__global__ void attn_kernel(const float* __restrict__ v, const float* __restrict__ a,
                            float* __restrict__ o) {
    int n = blockIdx.x;
    int tid = threadIdx.x; // 0..191
    int b = n / (HH * WW), rem = n % (HH * WW), h = rem / WW, w = rem % WW;
    __shared__ float p[FF];        // attention logits -> softmax probs
    __shared__ float vl[KK][CC];   // gathered v patches

    for (int f = tid; f < FF; f += CC) p[f] = a[n * FF + f];
    #pragma unroll
    for (int j = 0; j < KK; ++j) {
        int hh = h + j / 3 - 1, ww = w + j % 3 - 1;
        if (hh >= 0 && hh < HH && ww >= 0 && ww < WW)
            vl[j][tid] = v[((b * HH + hh) * WW + ww) * CC + tid];
        else
            vl[j][tid] = 0.f;
    }
    __syncthreads();

    if (tid < NHEADS * KK) {
        float* row = p + tid * KK;
        float t[KK];
        float m = -1e30f;
        #pragma unroll
        for (int j = 0; j < KK; ++j) { t[j] = row[j] * SCALE; m = fmaxf(m, t[j]); }
        float s = 0.f;
        #pragma unroll
        for (int j = 0; j < KK; ++j) { t[j] = __expf(t[j] - m); s += t[j]; }
        float inv = 1.f / s;
        #pragma unroll
        for (int j = 0; j < KK; ++j) row[j] = t[j] * inv;
    }
    __syncthreads();

    int head = tid / HD;
    const float* ph = p + head * 81;
    #pragma unroll
    for (int i = 0; i < KK; ++i) {
        float acc = 0.f;
        #pragma unroll
        for (int j = 0; j < KK; ++j) acc += ph[i * 9 + j] * vl[j][tid];
        o[(n * KK + i) * CC + tid] = acc;
    }
}

// folded[b,y,x,c] = sum over valid (ki,kj) of o[b, y+1-ki, x+1-kj, ki*3+kj, c]
__global__ void fold_kernel(const float* __restrict__ o, float* __restrict__ folded) {
    int idx = blockIdx.x * blockDim.x + threadIdx.x;
    if (idx >= NPIX * CC) return;
    int c = idx % CC, n = idx / CC;
    int b = n / (HH * WW), rem = n % (HH * WW), y = rem / WW, x = rem % WW;
    float s = 0.f;
    #pragma unroll
    for (int ki = 0; ki < 3; ++ki) {
        #pragma unroll
        for (int kj = 0; kj < 3; ++kj) {
            int hh = y + 1 - ki, ww = x + 1 - kj;
            if (hh >= 0 && hh < HH && ww >= 0 && ww < WW)
                s += o[(((b * HH + hh) * WW + ww) * KK + (ki * 3 + kj)) * CC + c];
        }
    }
    folded[idx] = s;
}

extern "C" void kernel_launch(void* const* d_in, const int* in_sizes, int n_in,
                              void* d_out, int out_size, void* d_ws, size_t ws_size,
                              hipStream_t stream) {
    const float* x   = (const float*)d_in[0];
    const float* vw  = (const float*)d_in[1];
    const float* aw  = (const float*)d_in[2];
    const float* ab  = (const float*)d_in[3];
    const float* pw  = (const float*)d_in[4];
    const float* pb  = (const float*)d_in[5];
    float* out = (float*)d_out;

    float* v      = (float*)d_ws;                 // NPIX*CC
    float* a      = v + (size_t)NPIX * CC;        // NPIX*FF
    float* o      = a + (size_t)NPIX * FF;        // NPIX*KK*CC
    float* folded = o + (size_t)NPIX * KK * CC;   // NPIX*CC

    dim3 blk(256);
    dim3 grid_v(NPIX / 64, (CC + 63) / 64);   // 72 x 3
    dim3 grid_a(NPIX / 64, (FF + 63) / 64);   // 72 x 8

    gemm_xwt_kernel<CC, false><<<grid_v, blk, 0, stream>>>(x, vw, nullptr, v);
    gemm_xwt_kernel<FF, true ><<<grid_a, blk, 0, stream>>>(x, aw, ab, a);
    attn_kernel<<<NPIX, CC, 0, stream>>>(v, a, o);
    fold_kernel<<<(NPIX * CC) / 256, 256, 0, stream>>>(o, folded);
    gemm_xwt_kernel<CC, true ><<<grid_v, blk, 0, stream>>>(folded, pw, pb, out);
}

// Round 6
// 111.526 us; speedup vs baseline: 6.5844x; 1.3351x over previous
//
#include <hip/hip_runtime.h>

#define BB 2
#define HH 48
#define WW 48
#define CC 192
#define NHEADS 6
#define HD 32
#define KK 9
#define FF 486
#define NPIX (BB*HH*WW)   // 4608
#define SCALE 0.17677669529663687f  // 1/sqrt(32)

typedef __bf16 bf16;
typedef __attribute__((ext_vector_type(4))) __bf16 bf16x4;
typedef __attribute__((ext_vector_type(8))) __bf16 bf16x8;
typedef __attribute__((ext_vector_type(4))) float f32x4;

#define BM 128
#define BN 64
#define KD 192
#define LDA 200   // padded LDS row stride in bf16 (400 B, 16B-aligned, bank-balanced)

// ---------------------------------------------------------------------------
// MFMA GEMM core: OUT[M][N] = X[M][K=192] * W[N][K]^T (+bias)
// whole-K staged in LDS as bf16. 256 threads = 4 waves, each wave 64x32.
// ---------------------------------------------------------------------------
__device__ __forceinline__ void gemm_core(
    const float* __restrict__ X, const float* __restrict__ W,
    const float* __restrict__ bias, float* __restrict__ OUT,
    int m0, int n0, int Ndim,
    bf16 (*As)[LDA], bf16 (*Bs)[LDA])
{
    const int tid = threadIdx.x;

    // stage A: BM x 192 fp32 -> bf16. 6144 float4 total, 24 per thread.
    #pragma unroll
    for (int i = 0; i < 24; ++i) {
        const int f = tid + i * 256;
        const int row = f / 48, colf = f % 48;
        const float4 xv = *(const float4*)(X + (size_t)(m0 + row) * KD + colf * 4);
        bf16x4 t = { (__bf16)xv.x, (__bf16)xv.y, (__bf16)xv.z, (__bf16)xv.w };
        *(bf16x4*)(&As[row][colf * 4]) = t;
    }
    // stage B: BN x 192 fp32 -> bf16. 3072 float4 total, 12 per thread.
    #pragma unroll
    for (int i = 0; i < 12; ++i) {
        const int f = tid + i * 256;
        const int row = f / 48, colf = f % 48;
        float4 wv = make_float4(0.f, 0.f, 0.f, 0.f);
        if (n0 + row < Ndim)
            wv = *(const float4*)(W + (size_t)(n0 + row) * KD + colf * 4);
        bf16x4 t = { (__bf16)wv.x, (__bf16)wv.y, (__bf16)wv.z, (__bf16)wv.w };
        *(bf16x4*)(&Bs[row][colf * 4]) = t;
    }
    __syncthreads();

    const int wave = tid >> 6, lane = tid & 63;
    const int wm = (wave >> 1) * 64;   // 0 / 64
    const int wn = (wave & 1) * 32;    // 0 / 32
    const int lrow = lane & 15;        // fragment row (A) / col (B,D)
    const int lk   = (lane >> 4) * 8;  // k-chunk of 8

    f32x4 acc[4][2] = {};
    #pragma unroll
    for (int ks = 0; ks < 6; ++ks) {
        bf16x8 bfr[2];
        #pragma unroll
        for (int j = 0; j < 2; ++j)
            bfr[j] = *(const bf16x8*)(&Bs[wn + j * 16 + lrow][ks * 32 + lk]);
        #pragma unroll
        for (int i = 0; i < 4; ++i) {
            bf16x8 afr = *(const bf16x8*)(&As[wm + i * 16 + lrow][ks * 32 + lk]);
            #pragma unroll
            for (int j = 0; j < 2; ++j)
                acc[i][j] = __builtin_amdgcn_mfma_f32_16x16x32_bf16(afr, bfr[j], acc[i][j], 0, 0, 0);
        }
    }

    const int crow = (lane >> 4) * 4;  // D row base = (lane>>4)*4 + reg
    #pragma unroll
    for (int j = 0; j < 2; ++j) {
        const int col = n0 + wn + j * 16 + lrow;
        if (col < Ndim) {
            const float bv = bias ? bias[col] : 0.f;
            #pragma unroll
            for (int i = 0; i < 4; ++i) {
                #pragma unroll
                for (int r = 0; r < 4; ++r) {
                    const int row = m0 + wm + i * 16 + crow + r;
                    OUT[(size_t)row * Ndim + col] = acc[i][j][r] + bv;
                }
            }
        }
    }
}

// fused v = x@vw^T  and  a = x@aw^T + ab   (blockIdx.y selects target)
__global__ __launch_bounds__(256) void gemm_va_kernel(
    const float* __restrict__ x, const float* __restrict__ vw,
    const float* __restrict__ aw, const float* __restrict__ ab,
    float* __restrict__ v, float* __restrict__ a)
{
    __shared__ bf16 As[BM][LDA];
    __shared__ bf16 Bs[BN][LDA];
    const int m0 = blockIdx.x * BM;
    const int by = blockIdx.y;
    if (by < 3) gemm_core(x, vw, nullptr, v, m0, by * 64, CC, As, Bs);
    else        gemm_core(x, aw, ab,      a, m0, (by - 3) * 64, FF, As, Bs);
}

__global__ __launch_bounds__(256) void gemm_proj_kernel(
    const float* __restrict__ folded, const float* __restrict__ pw,
    const float* __restrict__ pb, float* __restrict__ out)
{
    __shared__ bf16 As[BM][LDA];
    __shared__ bf16 Bs[BN][LDA];
    gemm_core(folded, pw, pb, out, blockIdx.x * BM, blockIdx.y * 64, CC, As, Bs);
}

// ---------------------------------------------------------------------------
// Per-pixel attention: one 192-thread block per pixel (fp32).
// ---------------------------------------------------------------------------
__global__ void attn_kernel(const float* __restrict__ v, const float* __restrict__ a,
                            float* __restrict__ o) {
    int n = blockIdx.x;
    int tid = threadIdx.x; // 0..191
    int b = n / (HH * WW), rem = n % (HH * WW), h = rem / WW, w = rem % WW;
    __shared__ float p[FF];
    __shared__ float vl[KK][CC];

    for (int f = tid; f < FF; f += CC) p[f] = a[n * FF + f];
    #pragma unroll
    for (int j = 0; j < KK; ++j) {
        int hh = h + j / 3 - 1, ww = w + j % 3 - 1;
        if (hh >= 0 && hh < HH && ww >= 0 && ww < WW)
            vl[j][tid] = v[((b * HH + hh) * WW + ww) * CC + tid];
        else
            vl[j][tid] = 0.f;
    }
    __syncthreads();

    if (tid < NHEADS * KK) {
        float* row = p + tid * KK;
        float t[KK];
        float m = -1e30f;
        #pragma unroll
        for (int j = 0; j < KK; ++j) { t[j] = row[j] * SCALE; m = fmaxf(m, t[j]); }
        float s = 0.f;
        #pragma unroll
        for (int j = 0; j < KK; ++j) { t[j] = __expf(t[j] - m); s += t[j]; }
        float inv = 1.f / s;
        #pragma unroll
        for (int j = 0; j < KK; ++j) row[j] = t[j] * inv;
    }
    __syncthreads();

    int head = tid / HD;
    const float* ph = p + head * 81;
    #pragma unroll
    for (int i = 0; i < KK; ++i) {
        float acc = 0.f;
        #pragma unroll
        for (int j = 0; j < KK; ++j) acc += ph[i * 9 + j] * vl[j][tid];
        o[(n * KK + i) * CC + tid] = acc;
    }
}

// folded[b,y,x,c] = sum over valid (ki,kj) of o[b, y+1-ki, x+1-kj, ki*3+kj, c]
__global__ void fold_kernel(const float* __restrict__ o, float* __restrict__ folded) {
    int idx = blockIdx.x * blockDim.x + threadIdx.x;
    if (idx >= NPIX * CC) return;
    int c = idx % CC, n = idx / CC;
    int b = n / (HH * WW), rem = n % (HH * WW), y = rem / WW, x = rem % WW;
    float s = 0.f;
    #pragma unroll
    for (int ki = 0; ki < 3; ++ki) {
        #pragma unroll
        for (int kj = 0; kj < 3; ++kj) {
            int hh = y + 1 - ki, ww = x + 1 - kj;
            if (hh >= 0 && hh < HH && ww >= 0 && ww < WW)
                s += o[(((b * HH + hh) * WW + ww) * KK + (ki * 3 + kj)) * CC + c];
        }
    }
    folded[idx] = s;
}

extern "C" void kernel_launch(void* const* d_in, const int* in_sizes, int n_in,
                              void* d_out, int out_size, void* d_ws, size_t ws_size,
                              hipStream_t stream) {
    const float* x   = (const float*)d_in[0];
    const float* vw  = (const float*)d_in[1];
    const float* aw  = (const float*)d_in[2];
    const float* ab  = (const float*)d_in[3];
    const float* pw  = (const float*)d_in[4];
    const float* pb  = (const float*)d_in[5];
    float* out = (float*)d_out;

    float* v      = (float*)d_ws;                 // NPIX*CC
    float* a      = v + (size_t)NPIX * CC;        // NPIX*FF
    float* o      = a + (size_t)NPIX * FF;        // NPIX*KK*CC
    float* folded = o + (size_t)NPIX * KK * CC;   // NPIX*CC

    dim3 blk(256);
    dim3 grid_va(NPIX / BM, 3 + 8);               // 36 x 11
    dim3 grid_pj(NPIX / BM, CC / BN);             // 36 x 3

    gemm_va_kernel<<<grid_va, blk, 0, stream>>>(x, vw, aw, ab, v, a);
    attn_kernel<<<NPIX, CC, 0, stream>>>(v, a, o);
    fold_kernel<<<(NPIX * CC) / 256, 256, 0, stream>>>(o, folded);
    gemm_proj_kernel<<<grid_pj, blk, 0, stream>>>(folded, pw, pb, out);
}